// Round 17
// baseline (71.728 us; speedup 1.0000x reference)
//
#include <hip/hip_runtime.h>
#include <hip/hip_bf16.h>

#define HW1K  1048576    // 1024*1024

typedef float  f4    __attribute__((ext_vector_type(4)));
typedef float  f32x4 __attribute__((ext_vector_type(4)));
typedef short  s16x8 __attribute__((ext_vector_type(8)));   // MFMA bf16 frag
typedef unsigned short u16x8 __attribute__((ext_vector_type(8)));

__device__ __forceinline__ float bf2f(unsigned short u) {
    unsigned int b = ((unsigned int)u) << 16;
    return __builtin_bit_cast(float, b);
}
// split x = hi + lo (both bf16, truncated): residual ~2^-16 relative.
__device__ __forceinline__ void fsplit(float x, unsigned short& h, unsigned short& l) {
    unsigned int xb = __builtin_bit_cast(unsigned int, x);
    h = (unsigned short)(xb >> 16);
    float fh = __builtin_bit_cast(float, xb & 0xffff0000u);
    float r = x - fh;
    l = (unsigned short)(__builtin_bit_cast(unsigned int, r) >> 16);
}

// ---------------------------------------------------------------------------
// Weight prep (L2..L6): OIHW fp32 -> W[co][Kp] bf16 hi/lo, k = kk*CIN+ci,
// Kp padded x32 with ZERO. Ranges (shorts): W2@0(32x160) W3@5120(32x288)
// W4@14336(64x288) W5@32768(64x576) W6@69632(96x576); total 124928.
__global__ __launch_bounds__(256)
void prep_wM(const float* __restrict__ w2, const float* __restrict__ w3,
             const float* __restrict__ w4, const float* __restrict__ w5,
             const float* __restrict__ w6,
             unsigned short* __restrict__ Wh, unsigned short* __restrict__ Wl) {
    int i = blockIdx.x * 256 + threadIdx.x;
    if (i >= 124928) return;
    const float* src; int base, cin, kp_;
    if      (i < 5120)  { src = w2; base = 0;     cin = 16; kp_ = 160; }
    else if (i < 14336) { src = w3; base = 5120;  cin = 32; kp_ = 288; }
    else if (i < 32768) { src = w4; base = 14336; cin = 32; kp_ = 288; }
    else if (i < 69632) { src = w5; base = 32768; cin = 64; kp_ = 576; }
    else                { src = w6; base = 69632; cin = 64; kp_ = 576; }
    int r  = i - base;
    int co = r / kp_;
    int kp = r % kp_;
    int kk = kp / cin;
    int ci = kp % cin;
    float v = (kk < 9) ? src[(co * cin + ci) * 9 + kk] : 0.0f;
    unsigned short h, l; fsplit(v, h, l);
    Wh[i] = h; Wl[i] = l;
}

// ---------------------------------------------------------------------------
// One MFMA conv layer, LDS -> LDS, 8 waves. nt = wid%NT, chunk = wid/NT
// streams m-tiles (critical path: max 2 pairs/wave). HOIST=1: B-fragments
// register-resident (KS<=9 -> <=72 VGPR, real reuse). HOIST=0 (L5: MT=1):
// stream B in the K-loop. In: [px][CINP=CIN+8] bf16 hi/lo. Split-bf16:
// 3 MFMAs (HH,HL,LH)/K-step. D: col=lane&15 (=co), row=4*(lane>>4)+j.
template <int WIN, int CIN, int COUT, int KP, int SO, int HOIST>
__device__ __forceinline__ void layerM(const unsigned short* sH, const unsigned short* sL,
                                       unsigned short* dH, unsigned short* dL,
                                       const unsigned short* __restrict__ Wh,
                                       const unsigned short* __restrict__ Wl,
                                       const float* __restrict__ bias) {
    constexpr int WOUT = WIN - 2;
    constexpr int NPX  = WOUT * WOUT;
    constexpr int CINP = CIN + 8;
    constexpr int MT   = (NPX + 15) / 16;
    constexpr int NT   = COUT / 16;          // 2 (L2,L3) or 4 (L4,L5)
    constexpr int WPN  = 8 / NT;             // waves per n-tile (8 waves)
    constexpr int KS   = KP / 32;

    const int wid  = threadIdx.x >> 6;
    const int lane = threadIdx.x & 63;
    const int m    = lane & 15;
    const int g    = lane >> 4;

    const int nt    = wid % NT;
    const int chunk = wid / NT;
    const int co    = nt * 16 + m;

    const unsigned short* wbh = Wh + (size_t)co * KP + 8 * g;
    const unsigned short* wbl = Wl + (size_t)co * KP + 8 * g;

    s16x8 bH[HOIST ? KS : 1], bL[HOIST ? KS : 1];
    if constexpr (HOIST) {
        #pragma unroll
        for (int k0 = 0; k0 < KS; ++k0) {
            bH[k0] = *(const s16x8*)(wbh + k0 * 32);
            bL[k0] = *(const s16x8*)(wbl + k0 * 32);
        }
    }
    const float bv = bias[co];

    #pragma unroll 1
    for (int mt = chunk; mt < MT; mt += WPN) {
        const int mt0 = mt * 16;
        int px = mt0 + m; if (px > NPX - 1) px = NPX - 1;
        const int pbase = (px / WOUT) * WIN + (px % WOUT);

        f32x4 aHH = {0,0,0,0}, aHL = {0,0,0,0}, aLH = {0,0,0,0};
        #pragma unroll
        for (int k0 = 0; k0 < KS; ++k0) {
            const int k   = k0 * 32 + 8 * g;
            const int kk  = k / CIN;             // power-of-2 shifts
            const int ci0 = k % CIN;
            const int aoff = (pbase + (kk / 3) * WIN + (kk % 3)) * CINP + ci0;
            s16x8 avh = *(const s16x8*)(&sH[aoff]);
            s16x8 avl = *(const s16x8*)(&sL[aoff]);
            s16x8 bvh, bvl;
            if constexpr (HOIST) { bvh = bH[k0]; bvl = bL[k0]; }
            else {
                bvh = *(const s16x8*)(wbh + k0 * 32);
                bvl = *(const s16x8*)(wbl + k0 * 32);
            }
            aHH = __builtin_amdgcn_mfma_f32_16x16x32_bf16(avh, bvh, aHH, 0, 0, 0);
            aHL = __builtin_amdgcn_mfma_f32_16x16x32_bf16(avh, bvl, aHL, 0, 0, 0);
            aLH = __builtin_amdgcn_mfma_f32_16x16x32_bf16(avl, bvh, aLH, 0, 0, 0);
        }
        #pragma unroll
        for (int j = 0; j < 4; ++j) {
            int opx = mt0 + g * 4 + j;
            if (opx < NPX) {
                float v = fmaxf(aHH[j] + aHL[j] + aLH[j] + bv, 0.0f);
                unsigned short h, l; fsplit(v, h, l);
                dH[opx * SO + co] = h;
                dL[opx * SO + co] = l;
            }
        }
    }
}

// ---------------------------------------------------------------------------
// Fused cone + conv1(VALU) + conv2..conv5(MFMA, LDS ping-pong) + folded
// 2x2 pool -> P6 global. Block = cell, 512 threads (8 waves): per-layer
// critical path halves vs 4 waves (R16 showed occupancy is not the lever;
// in-block chain length is). LDS ~34KB; (512,2) -> 128-VGPR cap, demand
// ~120 (hoists capped at KS<=9) -> no spill (check WRITE_SIZE).
__global__ __launch_bounds__(512, 2)
void fusedM(const float* __restrict__ x, const float* __restrict__ w1,
            const float* __restrict__ b1,
            const unsigned short* __restrict__ Wh, const unsigned short* __restrict__ Wl,
            const float* __restrict__ b2, const float* __restrict__ b3,
            const float* __restrict__ b4, const float* __restrict__ b5,
            unsigned short* __restrict__ P6h, unsigned short* __restrict__ P6l) {
    __shared__ float sC[592];                                    // cone [ci][196]
    __shared__ __align__(16) unsigned short AH[3840], AL[3840];  // t1[160][24] / t3[64][40] / t5[16][72]
    __shared__ __align__(16) unsigned short BH[4000], BL[4000];  // t2[100][40] / t4[36][72]

    const int cell = blockIdx.x;
    const int b = cell >> 8, gy = (cell >> 4) & 15, gx = cell & 15;

    // cone: sC[c][196]; xlow[y][x] = avg of x rows 4y+1..4y+2, cols 4x+1..4x+2.
    for (int i = threadIdx.x; i < 588; i += 512) {
        int c = i / 196, t = i % 196;
        int xi = t % 14, yi = t / 14;
        int ya = 16 * gy + 1 + yi, xa = 16 * gx + 1 + xi;
        const float* p = x + ((size_t)(b * 3 + c)) * HW1K + (4 * ya + 1) * 1024 + (4 * xa + 1);
        sC[i] = 0.25f * (p[0] + p[1] + p[1024] + p[1025]);
    }
    // zero t1 margin rows 144..159 (read by L2's kk=9 zero-weight taps)
    for (int i = threadIdx.x; i < 384; i += 512) { AH[3456 + i] = 0; AL[3456 + i] = 0; }
    __syncthreads();

    // conv1 (VALU), 8 waves: co-group = wid&3 (4 co each), strip-half =
    // wid>>2 (half 0: strips {0,2}; half 1: strip {1}); 144 px total.
    {
        const int wid  = __builtin_amdgcn_readfirstlane(threadIdx.x >> 6);
        const int lane = threadIdx.x & 63;
        const int co0  = (wid & 3) * 4;
        const int s0   = wid >> 2;
        #pragma unroll 1
        for (int s = s0; s < 3; s += 2) {
            int px = lane + s * 64; if (px > 143) px = 143;
            const int pb = (px / 12) * 14 + (px % 12);
            f4 acc;
            #pragma unroll
            for (int j = 0; j < 4; ++j) acc[j] = b1[co0 + j];
            for (int ci = 0; ci < 3; ++ci)
                #pragma unroll
                for (int k = 0; k < 9; ++k) {
                    float w[4];
                    #pragma unroll
                    for (int j = 0; j < 4; ++j) w[j] = w1[((co0 + j) * 3 + ci) * 9 + k];
                    float a = sC[ci * 196 + pb + (k / 3) * 14 + (k % 3)];
                    #pragma unroll
                    for (int j = 0; j < 4; ++j) acc[j] = fmaf(w[j], a, acc[j]);
                }
            #pragma unroll
            for (int j = 0; j < 4; ++j) {
                float v = fmaxf(acc[j], 0.0f);
                unsigned short h, l; fsplit(v, h, l);
                AH[px * 24 + co0 + j] = h;
                AL[px * 24 + co0 + j] = l;
            }
        }
    }
    __syncthreads();

    layerM<12, 16, 32, 160, 40, 1>(AH, AL, BH, BL, Wh + 0,     Wl + 0,     b2);
    __syncthreads();
    layerM<10, 32, 32, 288, 40, 1>(BH, BL, AH, AL, Wh + 5120,  Wl + 5120,  b3);
    __syncthreads();
    layerM< 8, 32, 64, 288, 72, 1>(AH, AL, BH, BL, Wh + 14336, Wl + 14336, b4);
    __syncthreads();
    layerM< 6, 64, 64, 576, 72, 0>(BH, BL, AH, AL, Wh + 32768, Wl + 32768, b5);
    __syncthreads();

    // folded pool: P6[cell][kk*64+ci] = 0.25 * sum_{dr,dc} t5[(kk/3+dr)*4+(kk%3+dc)][ci]
    for (int t = threadIdx.x; t < 576; t += 512) {
        int kk = t >> 6, ci = t & 63;
        int ky = kk / 3, kx = kk % 3;
        float v = 0.0f;
        #pragma unroll
        for (int dr = 0; dr < 2; ++dr)
            #pragma unroll
            for (int dc = 0; dc < 2; ++dc) {
                int px = (ky + dr) * 4 + (kx + dc);
                v += bf2f(AH[px * 72 + ci]) + bf2f(AL[px * 72 + ci]);
            }
        v *= 0.25f;
        unsigned short h, l; fsplit(v, h, l);
        P6h[(size_t)cell * 576 + t] = h;
        P6l[(size_t)cell * 576 + t] = l;
    }
}

// ---------------------------------------------------------------------------
// L6 as GEMM: M=512 cells, K=576, N=96; 1-wave blocks, grid (32, 6).
__global__ __launch_bounds__(64)
void gemm6(const unsigned short* __restrict__ Bh, const unsigned short* __restrict__ Bl,
           const unsigned short* __restrict__ W6h, const unsigned short* __restrict__ W6l,
           const float* __restrict__ b6, float* __restrict__ c16) {
    const int cell0 = blockIdx.x * 16;
    const int co0   = blockIdx.y * 16;
    const int lane  = threadIdx.x;
    const int m = lane & 15, g = lane >> 4;

    const unsigned short* pah = Bh  + (size_t)(cell0 + m) * 576 + 8 * g;
    const unsigned short* pal = Bl  + (size_t)(cell0 + m) * 576 + 8 * g;
    const unsigned short* pbh = W6h + (size_t)(co0 + m) * 576 + 8 * g;
    const unsigned short* pbl = W6l + (size_t)(co0 + m) * 576 + 8 * g;

    f32x4 aHH = {0,0,0,0}, aHL = {0,0,0,0}, aLH = {0,0,0,0};
    #pragma unroll 6
    for (int k0 = 0; k0 < 576; k0 += 32) {
        s16x8 avh = *(const s16x8*)(pah + k0);
        s16x8 avl = *(const s16x8*)(pal + k0);
        s16x8 bvh = *(const s16x8*)(pbh + k0);
        s16x8 bvl = *(const s16x8*)(pbl + k0);
        aHH = __builtin_amdgcn_mfma_f32_16x16x32_bf16(avh, bvh, aHH, 0, 0, 0);
        aHL = __builtin_amdgcn_mfma_f32_16x16x32_bf16(avh, bvl, aHL, 0, 0, 0);
        aLH = __builtin_amdgcn_mfma_f32_16x16x32_bf16(avl, bvh, aLH, 0, 0, 0);
    }
    const int co = co0 + m;
    const float bv = b6[co];
    #pragma unroll
    for (int j = 0; j < 4; ++j) {
        int cell = cell0 + g * 4 + j;
        float v = aHH[j] + aHL[j] + aLH[j] + bv;
        int b = cell >> 8, gyx = cell & 255;
        c16[(size_t)b * 24576 + (gyx * 8 + (co & 7)) * 12 + (co >> 3)] = v;
    }
}

// ---------------------------------------------------------------------------
// Fused guide + trilinear slice + affine + clip; 4 px per thread.
__global__ __launch_bounds__(256)
void slice_apply4(const float* __restrict__ x, const float* __restrict__ c16,
                  float* __restrict__ out) {
    int t = blockIdx.x * 256 + threadIdx.x;
    int po4 = t * 4;
    int b   = po4 >> 20;
    int po  = po4 & (HW1K - 1);
    int py  = po >> 10;
    int px0 = po & 1023;

    const float* xb = x + (size_t)b * 3 * HW1K;
    f4 rv  = *(const f4*)(xb + po);
    f4 gv  = *(const f4*)(xb + HW1K + po);
    f4 bv  = *(const f4*)(xb + 2 * HW1K + po);

    float ysf = (float)py * (15.0f / 1023.0f);
    int y0 = (int)floorf(ysf); int y1 = min(y0 + 1, 15);
    float wy = ysf - (float)y0;

    const float* gb = c16 + (size_t)b * 24576;
    f4 outv[3];

    #pragma unroll
    for (int s = 0; s < 4; ++s) {
        float r  = rv[s], g = gv[s], bl = bv[s];
        int   px = px0 + s;

        float gd = fminf(fmaxf(0.299f * r + 0.587f * g + 0.114f * bl, 0.0f), 1.0f);

        float xsf = (float)px * (15.0f / 1023.0f);
        int x0 = (int)floorf(xsf); int x1 = min(x0 + 1, 15);
        float wx = xsf - (float)x0;

        float d  = gd * 7.0f;
        int d0 = (int)floorf(d); d0 = max(0, min(d0, 7));
        int d1 = min(d0 + 1, 7);
        float wd = fminf(fmaxf(d - (float)d0, 0.0f), 1.0f);

        float co[12];
        #pragma unroll
        for (int p = 0; p < 12; ++p) co[p] = 0.0f;

        #pragma unroll
        for (int cy = 0; cy < 2; ++cy) {
            int   yy  = cy ? y1 : y0;
            float wyf = cy ? wy : 1.0f - wy;
            #pragma unroll
            for (int cx = 0; cx < 2; ++cx) {
                int   xx  = cx ? x1 : x0;
                float wyx = wyf * (cx ? wx : 1.0f - wx);
                const float* g0 = gb + ((yy * 16 + xx) * 8 + d0) * 12;
                const float* g1 = gb + ((yy * 16 + xx) * 8 + d1) * 12;
                float wA = wyx * (1.0f - wd), wB = wyx * wd;
                #pragma unroll
                for (int p = 0; p < 12; ++p) co[p] += wA * g0[p] + wB * g1[p];
            }
        }

        #pragma unroll
        for (int i = 0; i < 3; ++i) {
            float v = co[i * 4 + 0] * r + co[i * 4 + 1] * g + co[i * 4 + 2] * bl + co[i * 4 + 3];
            outv[i][s] = fminf(fmaxf(v, 0.0f), 1.0f);
        }
    }

    float* ob = out + (size_t)b * 3 * HW1K;
    #pragma unroll
    for (int i = 0; i < 3; ++i)
        *(f4*)(ob + i * HW1K + po) = outv[i];
}

// ---------------------------------------------------------------------------
extern "C" void kernel_launch(void* const* d_in, const int* in_sizes, int n_in,
                              void* d_out, int out_size, void* d_ws, size_t ws_size,
                              hipStream_t stream) {
    const float* x  = (const float*)d_in[0];
    const float* w1 = (const float*)d_in[1];  const float* b1 = (const float*)d_in[2];
    const float* w2 = (const float*)d_in[3];  const float* b2 = (const float*)d_in[4];
    const float* w3 = (const float*)d_in[5];  const float* b3 = (const float*)d_in[6];
    const float* w4 = (const float*)d_in[7];  const float* b4 = (const float*)d_in[8];
    const float* w5 = (const float*)d_in[9];  const float* b5 = (const float*)d_in[10];
    const float* w6 = (const float*)d_in[11]; const float* b6 = (const float*)d_in[12];
    float* out = (float*)d_out;

    char* w = (char*)d_ws;
    unsigned short* Wh  = (unsigned short*)w;   w += 124928 * 2;
    unsigned short* Wl  = (unsigned short*)w;   w += 124928 * 2;
    unsigned short* P6h = (unsigned short*)w;   w += 512 * 576 * 2;
    unsigned short* P6l = (unsigned short*)w;   w += 512 * 576 * 2;
    float*          c16 = (float*)w;

    prep_wM<<<dim3(489),  dim3(256), 0, stream>>>(w2, w3, w4, w5, w6, Wh, Wl);
    fusedM <<<dim3(512),  dim3(512), 0, stream>>>(x, w1, b1, Wh, Wl, b2, b3, b4, b5, P6h, P6l);
    gemm6  <<<dim3(32, 6), dim3(64), 0, stream>>>(P6h, P6l, Wh + 69632, Wl + 69632, b6, c16);
    slice_apply4<<<dim3(2 * HW1K / 4 / 256), dim3(256), 0, stream>>>(x, c16, out);

    (void)in_sizes; (void)n_in; (void)out_size; (void)ws_size;
}

// Round 18
// 66.605 us; speedup vs baseline: 1.0769x; 1.0769x over previous
//
#include <hip/hip_runtime.h>
#include <hip/hip_bf16.h>

#define HW1K  1048576    // 1024*1024

typedef float  f4    __attribute__((ext_vector_type(4)));
typedef float  f32x4 __attribute__((ext_vector_type(4)));
typedef short  s16x8 __attribute__((ext_vector_type(8)));   // MFMA bf16 frag
typedef unsigned short u16x8 __attribute__((ext_vector_type(8)));

__device__ __forceinline__ float bf2f(unsigned short u) {
    unsigned int b = ((unsigned int)u) << 16;
    return __builtin_bit_cast(float, b);
}
// split x = hi + lo (both bf16, truncated): residual ~2^-16 relative.
__device__ __forceinline__ void fsplit(float x, unsigned short& h, unsigned short& l) {
    unsigned int xb = __builtin_bit_cast(unsigned int, x);
    h = (unsigned short)(xb >> 16);
    float fh = __builtin_bit_cast(float, xb & 0xffff0000u);
    float r = x - fh;
    l = (unsigned short)(__builtin_bit_cast(unsigned int, r) >> 16);
}

// ---------------------------------------------------------------------------
// Weight prep (L2..L6): OIHW fp32 -> W[co][Kp] bf16 hi/lo, k = kk*CIN+ci,
// Kp padded x32 with ZERO. Ranges (shorts): W2@0(32x160) W3@5120(32x288)
// W4@14336(64x288) W5@32768(64x576) W6@69632(96x576); total 124928.
__global__ __launch_bounds__(256)
void prep_wM(const float* __restrict__ w2, const float* __restrict__ w3,
             const float* __restrict__ w4, const float* __restrict__ w5,
             const float* __restrict__ w6,
             unsigned short* __restrict__ Wh, unsigned short* __restrict__ Wl) {
    int i = blockIdx.x * 256 + threadIdx.x;
    if (i >= 124928) return;
    const float* src; int base, cin, kp_;
    if      (i < 5120)  { src = w2; base = 0;     cin = 16; kp_ = 160; }
    else if (i < 14336) { src = w3; base = 5120;  cin = 32; kp_ = 288; }
    else if (i < 32768) { src = w4; base = 14336; cin = 32; kp_ = 288; }
    else if (i < 69632) { src = w5; base = 32768; cin = 64; kp_ = 576; }
    else                { src = w6; base = 69632; cin = 64; kp_ = 576; }
    int r  = i - base;
    int co = r / kp_;
    int kp = r % kp_;
    int kk = kp / cin;
    int ci = kp % cin;
    float v = (kk < 9) ? src[(co * cin + ci) * 9 + kk] : 0.0f;
    unsigned short h, l; fsplit(v, h, l);
    Wh[i] = h; Wl[i] = l;
}

// ---------------------------------------------------------------------------
// One MFMA conv layer, LDS -> LDS, 4 waves. Wave = (nt = wid%NT, chunk =
// wid/NT); B-fragments for the wave's n-tile loaded ONCE into registers
// (real reuse across MT/WPN m-tiles), m-tiles streamed against them.
// In: [px][CINP=CIN+8] bf16 hi/lo (contiguous 16B A-frag = 1 ds_read_b128).
// Split-bf16: 3 MFMAs (HH,HL,LH)/K-step. D: col=lane&15 (=co),
// row=4*(lane>>4)+j  [m89-verified C/D layout].
template <int WIN, int CIN, int COUT, int KP, int SO>
__device__ __forceinline__ void layerM(const unsigned short* sH, const unsigned short* sL,
                                       unsigned short* dH, unsigned short* dL,
                                       const unsigned short* __restrict__ Wh,
                                       const unsigned short* __restrict__ Wl,
                                       const float* __restrict__ bias) {
    constexpr int WOUT = WIN - 2;
    constexpr int NPX  = WOUT * WOUT;
    constexpr int CINP = CIN + 8;
    constexpr int MT   = (NPX + 15) / 16;
    constexpr int NT   = COUT / 16;          // 2 (L2,L3) or 4 (L4,L5)
    constexpr int WPN  = 4 / NT;             // waves per n-tile
    constexpr int KS   = KP / 32;

    const int wid  = threadIdx.x >> 6;
    const int lane = threadIdx.x & 63;
    const int m    = lane & 15;
    const int g    = lane >> 4;

    const int nt    = wid % NT;
    const int chunk = wid / NT;
    const int co    = nt * 16 + m;

    // B fragments for this wave's n-tile: loaded once, register-resident.
    s16x8 bH[KS], bL[KS];
    {
        const unsigned short* wbh = Wh + (size_t)co * KP + 8 * g;
        const unsigned short* wbl = Wl + (size_t)co * KP + 8 * g;
        #pragma unroll
        for (int k0 = 0; k0 < KS; ++k0) {
            bH[k0] = *(const s16x8*)(wbh + k0 * 32);
            bL[k0] = *(const s16x8*)(wbl + k0 * 32);
        }
    }
    const float bv = bias[co];

    #pragma unroll 1
    for (int mt = chunk; mt < MT; mt += WPN) {
        const int mt0 = mt * 16;
        int px = mt0 + m; if (px > NPX - 1) px = NPX - 1;
        const int pbase = (px / WOUT) * WIN + (px % WOUT);

        f32x4 aHH = {0,0,0,0}, aHL = {0,0,0,0}, aLH = {0,0,0,0};
        #pragma unroll
        for (int k0 = 0; k0 < KS; ++k0) {
            const int k   = k0 * 32 + 8 * g;
            const int kk  = k / CIN;             // power-of-2 shifts
            const int ci0 = k % CIN;
            const int aoff = (pbase + (kk / 3) * WIN + (kk % 3)) * CINP + ci0;
            s16x8 avh = *(const s16x8*)(&sH[aoff]);
            s16x8 avl = *(const s16x8*)(&sL[aoff]);
            aHH = __builtin_amdgcn_mfma_f32_16x16x32_bf16(avh, bH[k0], aHH, 0, 0, 0);
            aHL = __builtin_amdgcn_mfma_f32_16x16x32_bf16(avh, bL[k0], aHL, 0, 0, 0);
            aLH = __builtin_amdgcn_mfma_f32_16x16x32_bf16(avl, bH[k0], aLH, 0, 0, 0);
        }
        #pragma unroll
        for (int j = 0; j < 4; ++j) {
            int opx = mt0 + g * 4 + j;
            if (opx < NPX) {
                float v = fmaxf(aHH[j] + aHL[j] + aLH[j] + bv, 0.0f);
                unsigned short h, l; fsplit(v, h, l);
                dH[opx * SO + co] = h;
                dL[opx * SO + co] = l;
            }
        }
    }
}

// ---------------------------------------------------------------------------
// Fused cone + conv1(VALU) + conv2..conv5(MFMA, LDS ping-pong) + folded
// 2x2 pool -> P6 (L6's pooled A-matrix) global. Block = cell, 4 waves.
// LDS ~34KB. (256,2): 256-VGPR headroom for the B-hoists (R15 optimum;
// (256,3) trim was neutral, 8-wave split regressed).
__global__ __launch_bounds__(256, 2)
void fusedM(const float* __restrict__ x, const float* __restrict__ w1,
            const float* __restrict__ b1,
            const unsigned short* __restrict__ Wh, const unsigned short* __restrict__ Wl,
            const float* __restrict__ b2, const float* __restrict__ b3,
            const float* __restrict__ b4, const float* __restrict__ b5,
            unsigned short* __restrict__ P6h, unsigned short* __restrict__ P6l) {
    __shared__ float sC[592];                                    // cone [ci][196]
    __shared__ __align__(16) unsigned short AH[3840], AL[3840];  // t1[160][24] / t3[64][40] / t5[16][72]
    __shared__ __align__(16) unsigned short BH[4000], BL[4000];  // t2[100][40] / t4[36][72]

    const int cell = blockIdx.x;
    const int b = cell >> 8, gy = (cell >> 4) & 15, gx = cell & 15;

    // cone: sC[c][196]; xlow[y][x] = avg of x rows 4y+1..4y+2, cols 4x+1..4x+2.
    for (int i = threadIdx.x; i < 588; i += 256) {
        int c = i / 196, t = i % 196;
        int xi = t % 14, yi = t / 14;
        int ya = 16 * gy + 1 + yi, xa = 16 * gx + 1 + xi;
        const float* p = x + ((size_t)(b * 3 + c)) * HW1K + (4 * ya + 1) * 1024 + (4 * xa + 1);
        sC[i] = 0.25f * (p[0] + p[1] + p[1024] + p[1025]);
    }
    // zero t1 margin rows 144..159 (read by L2's kk=9 zero-weight taps)
    for (int i = threadIdx.x; i < 384; i += 256) { AH[3456 + i] = 0; AL[3456 + i] = 0; }
    __syncthreads();

    // conv1 (VALU): wave=4 co, lanes=px (3 strips). out t1 [px][24] hi/lo.
    {
        const int wid  = __builtin_amdgcn_readfirstlane(threadIdx.x >> 6);
        const int lane = threadIdx.x & 63;
        const int co0  = wid * 4;
        float acc[3][4]; int pxs[3], pb[3];
        #pragma unroll
        for (int t = 0; t < 3; ++t) {
            int px = lane + t * 64; if (px > 143) px = 143;
            pxs[t] = px; pb[t] = (px / 12) * 14 + (px % 12);
            #pragma unroll
            for (int j = 0; j < 4; ++j) acc[t][j] = b1[co0 + j];
        }
        for (int ci = 0; ci < 3; ++ci)
            #pragma unroll
            for (int k = 0; k < 9; ++k) {
                float w[4];
                #pragma unroll
                for (int j = 0; j < 4; ++j) w[j] = w1[((co0 + j) * 3 + ci) * 9 + k];
                const int ko = (k / 3) * 14 + (k % 3);
                #pragma unroll
                for (int t = 0; t < 3; ++t) {
                    float a = sC[ci * 196 + pb[t] + ko];
                    #pragma unroll
                    for (int j = 0; j < 4; ++j) acc[t][j] = fmaf(w[j], a, acc[t][j]);
                }
            }
        #pragma unroll
        for (int t = 0; t < 3; ++t)
            #pragma unroll
            for (int j = 0; j < 4; ++j) {
                float v = fmaxf(acc[t][j], 0.0f);
                unsigned short h, l; fsplit(v, h, l);
                AH[pxs[t] * 24 + co0 + j] = h;
                AL[pxs[t] * 24 + co0 + j] = l;
            }
    }
    __syncthreads();

    layerM<12, 16, 32, 160, 40>(AH, AL, BH, BL, Wh + 0,     Wl + 0,     b2);
    __syncthreads();
    layerM<10, 32, 32, 288, 40>(BH, BL, AH, AL, Wh + 5120,  Wl + 5120,  b3);
    __syncthreads();
    layerM< 8, 32, 64, 288, 72>(AH, AL, BH, BL, Wh + 14336, Wl + 14336, b4);
    __syncthreads();
    layerM< 6, 64, 64, 576, 72>(BH, BL, AH, AL, Wh + 32768, Wl + 32768, b5);
    __syncthreads();

    // folded pool: P6[cell][kk*64+ci] = 0.25 * sum_{dr,dc} t5[(kk/3+dr)*4+(kk%3+dc)][ci]
    for (int t = threadIdx.x; t < 576; t += 256) {
        int kk = t >> 6, ci = t & 63;
        int ky = kk / 3, kx = kk % 3;
        float v = 0.0f;
        #pragma unroll
        for (int dr = 0; dr < 2; ++dr)
            #pragma unroll
            for (int dc = 0; dc < 2; ++dc) {
                int px = (ky + dr) * 4 + (kx + dc);
                v += bf2f(AH[px * 72 + ci]) + bf2f(AL[px * 72 + ci]);
            }
        v *= 0.25f;
        unsigned short h, l; fsplit(v, h, l);
        P6h[(size_t)cell * 576 + t] = h;
        P6l[(size_t)cell * 576 + t] = l;
    }
}

// ---------------------------------------------------------------------------
// L6 as GEMM: M=512 cells, K=576, N=96; 1-wave blocks, grid (32, 6).
// unroll 6: 24 loads issue per batch (latency amortized at <1 wave/CU).
__global__ __launch_bounds__(64)
void gemm6(const unsigned short* __restrict__ Bh, const unsigned short* __restrict__ Bl,
           const unsigned short* __restrict__ W6h, const unsigned short* __restrict__ W6l,
           const float* __restrict__ b6, float* __restrict__ c16) {
    const int cell0 = blockIdx.x * 16;
    const int co0   = blockIdx.y * 16;
    const int lane  = threadIdx.x;
    const int m = lane & 15, g = lane >> 4;

    const unsigned short* pah = Bh  + (size_t)(cell0 + m) * 576 + 8 * g;
    const unsigned short* pal = Bl  + (size_t)(cell0 + m) * 576 + 8 * g;
    const unsigned short* pbh = W6h + (size_t)(co0 + m) * 576 + 8 * g;
    const unsigned short* pbl = W6l + (size_t)(co0 + m) * 576 + 8 * g;

    f32x4 aHH = {0,0,0,0}, aHL = {0,0,0,0}, aLH = {0,0,0,0};
    #pragma unroll 6
    for (int k0 = 0; k0 < 576; k0 += 32) {
        s16x8 avh = *(const s16x8*)(pah + k0);
        s16x8 avl = *(const s16x8*)(pal + k0);
        s16x8 bvh = *(const s16x8*)(pbh + k0);
        s16x8 bvl = *(const s16x8*)(pbl + k0);
        aHH = __builtin_amdgcn_mfma_f32_16x16x32_bf16(avh, bvh, aHH, 0, 0, 0);
        aHL = __builtin_amdgcn_mfma_f32_16x16x32_bf16(avh, bvl, aHL, 0, 0, 0);
        aLH = __builtin_amdgcn_mfma_f32_16x16x32_bf16(avl, bvh, aLH, 0, 0, 0);
    }
    const int co = co0 + m;
    const float bv = b6[co];
    #pragma unroll
    for (int j = 0; j < 4; ++j) {
        int cell = cell0 + g * 4 + j;
        float v = aHH[j] + aHL[j] + aLH[j] + bv;
        int b = cell >> 8, gyx = cell & 255;
        c16[(size_t)b * 24576 + (gyx * 8 + (co & 7)) * 12 + (co >> 3)] = v;
    }
}

// ---------------------------------------------------------------------------
// Fused guide + trilinear slice + affine + clip; 4 px per thread.
__global__ __launch_bounds__(256)
void slice_apply4(const float* __restrict__ x, const float* __restrict__ c16,
                  float* __restrict__ out) {
    int t = blockIdx.x * 256 + threadIdx.x;
    int po4 = t * 4;
    int b   = po4 >> 20;
    int po  = po4 & (HW1K - 1);
    int py  = po >> 10;
    int px0 = po & 1023;

    const float* xb = x + (size_t)b * 3 * HW1K;
    f4 rv  = *(const f4*)(xb + po);
    f4 gv  = *(const f4*)(xb + HW1K + po);
    f4 bv  = *(const f4*)(xb + 2 * HW1K + po);

    float ysf = (float)py * (15.0f / 1023.0f);
    int y0 = (int)floorf(ysf); int y1 = min(y0 + 1, 15);
    float wy = ysf - (float)y0;

    const float* gb = c16 + (size_t)b * 24576;
    f4 outv[3];

    #pragma unroll
    for (int s = 0; s < 4; ++s) {
        float r  = rv[s], g = gv[s], bl = bv[s];
        int   px = px0 + s;

        float gd = fminf(fmaxf(0.299f * r + 0.587f * g + 0.114f * bl, 0.0f), 1.0f);

        float xsf = (float)px * (15.0f / 1023.0f);
        int x0 = (int)floorf(xsf); int x1 = min(x0 + 1, 15);
        float wx = xsf - (float)x0;

        float d  = gd * 7.0f;
        int d0 = (int)floorf(d); d0 = max(0, min(d0, 7));
        int d1 = min(d0 + 1, 7);
        float wd = fminf(fmaxf(d - (float)d0, 0.0f), 1.0f);

        float co[12];
        #pragma unroll
        for (int p = 0; p < 12; ++p) co[p] = 0.0f;

        #pragma unroll
        for (int cy = 0; cy < 2; ++cy) {
            int   yy  = cy ? y1 : y0;
            float wyf = cy ? wy : 1.0f - wy;
            #pragma unroll
            for (int cx = 0; cx < 2; ++cx) {
                int   xx  = cx ? x1 : x0;
                float wyx = wyf * (cx ? wx : 1.0f - wx);
                const float* g0 = gb + ((yy * 16 + xx) * 8 + d0) * 12;
                const float* g1 = gb + ((yy * 16 + xx) * 8 + d1) * 12;
                float wA = wyx * (1.0f - wd), wB = wyx * wd;
                #pragma unroll
                for (int p = 0; p < 12; ++p) co[p] += wA * g0[p] + wB * g1[p];
            }
        }

        #pragma unroll
        for (int i = 0; i < 3; ++i) {
            float v = co[i * 4 + 0] * r + co[i * 4 + 1] * g + co[i * 4 + 2] * bl + co[i * 4 + 3];
            outv[i][s] = fminf(fmaxf(v, 0.0f), 1.0f);
        }
    }

    float* ob = out + (size_t)b * 3 * HW1K;
    #pragma unroll
    for (int i = 0; i < 3; ++i)
        *(f4*)(ob + i * HW1K + po) = outv[i];
}

// ---------------------------------------------------------------------------
extern "C" void kernel_launch(void* const* d_in, const int* in_sizes, int n_in,
                              void* d_out, int out_size, void* d_ws, size_t ws_size,
                              hipStream_t stream) {
    const float* x  = (const float*)d_in[0];
    const float* w1 = (const float*)d_in[1];  const float* b1 = (const float*)d_in[2];
    const float* w2 = (const float*)d_in[3];  const float* b2 = (const float*)d_in[4];
    const float* w3 = (const float*)d_in[5];  const float* b3 = (const float*)d_in[6];
    const float* w4 = (const float*)d_in[7];  const float* b4 = (const float*)d_in[8];
    const float* w5 = (const float*)d_in[9];  const float* b5 = (const float*)d_in[10];
    const float* w6 = (const float*)d_in[11]; const float* b6 = (const float*)d_in[12];
    float* out = (float*)d_out;

    char* w = (char*)d_ws;
    unsigned short* Wh  = (unsigned short*)w;   w += 124928 * 2;
    unsigned short* Wl  = (unsigned short*)w;   w += 124928 * 2;
    unsigned short* P6h = (unsigned short*)w;   w += 512 * 576 * 2;
    unsigned short* P6l = (unsigned short*)w;   w += 512 * 576 * 2;
    float*          c16 = (float*)w;

    prep_wM<<<dim3(489),  dim3(256), 0, stream>>>(w2, w3, w4, w5, w6, Wh, Wl);
    fusedM <<<dim3(512),  dim3(256), 0, stream>>>(x, w1, b1, Wh, Wl, b2, b3, b4, b5, P6h, P6l);
    gemm6  <<<dim3(32, 6), dim3(64), 0, stream>>>(P6h, P6l, Wh + 69632, Wl + 69632, b6, c16);
    slice_apply4<<<dim3(2 * HW1K / 4 / 256), dim3(256), 0, stream>>>(x, c16, out);

    (void)in_sizes; (void)n_in; (void)out_size; (void)ws_size;
}